// Round 1
// 274.227 us; speedup vs baseline: 1.0846x; 1.0846x over previous
//
#include <hip/hip_runtime.h>
#include <math.h>

#define N_NODES 50000
#define N_EDGES 800000
#define IN_DIM 32
#define HIDDEN 64
#define Z_DIM 32
#define SCAN_B 256
#define NB_SCAN ((N_NODES + SCAN_B - 1) / SCAN_B)   // 196
#define N_XCD 8
#define NPX ((N_NODES + N_XCD - 1) / N_XCD)         // 6250 nodes per XCD range
#define SLICE 2048
#define N_SLICE ((N_EDGES + SLICE - 1) / SLICE)     // 391
#define SCAT_B (N_SLICE * N_XCD)                    // 3128 scatter blocks
#define FB 2048                                     // 8192 waves for node kernels

// bf16 (stored as ushort) <-> f32 helpers, RNE
__device__ __forceinline__ float bf2f(unsigned short u) {
    return __uint_as_float(((unsigned int)u) << 16);
}
__device__ __forceinline__ unsigned short f2bf(float f) {
    unsigned int u = __float_as_uint(f);
    u += 0x7fffu + ((u >> 16) & 1u);
    return (unsigned short)(u >> 16);
}

// wave-local edge dtype detect: int64 LE values < 2^31 have all-zero odd words.
__device__ __forceinline__ int detect64(const int* raw) {
    int lane = threadIdx.x & 63;
    int odd = raw[2 * lane + 1];
    unsigned long long b = __ballot(odd != 0);
    return (b == 0ULL) ? 1 : 0;
}

// ---------------------------------------------------------------------------
// prep: x->bf16 convert + XCD-partitioned degree histogram + int32 edge
// compaction (ep0) + publish flag. Blocks < SCAT_B run a hist slice
// (xcd = b%8 owns dst range); the block with sl%8==xcd also writes the
// compacted int2 (s,d) for its slice -> scatter later reads 4B+4B not 8B+8B.
__global__ void prep_kernel(const float* __restrict__ x, unsigned short* __restrict__ xb,
                            const void* __restrict__ raw, int* __restrict__ flag,
                            int* __restrict__ cnt, int2* __restrict__ ep0) {
    int is64 = detect64((const int*)raw);
    int i = blockIdx.x * 256 + threadIdx.x;
    if (blockIdx.x == 0 && threadIdx.x == 0) *flag = is64;
    if (i < N_NODES * IN_DIM) xb[i] = f2bf(x[i]);
    if (blockIdx.x < SCAT_B) {
        int xcd = blockIdx.x % N_XCD;
        int sl  = blockIdx.x / N_XCD;
        int own = ((sl % N_XCD) == xcd) ? 1 : 0;    // designated compactor
        int lo  = xcd * NPX, hi = lo + NPX;
        int base = sl * SLICE;
#pragma unroll
        for (int j = 0; j < SLICE / 256; j++) {
            int e = base + j * 256 + threadIdx.x;
            if (e < N_EDGES) {
                int d = is64 ? (int)((const long long*)raw)[N_EDGES + e]
                             : ((const int*)raw)[N_EDGES + e];
                if (own) {
                    int s = is64 ? (int)((const long long*)raw)[e]
                                 : ((const int*)raw)[e];
                    ep0[e] = make_int2(s, d);
                }
                if (d >= lo && d < hi) atomicAdd(&cnt[d], 1);
            }
        }
    }
}

// ---------------------------------------------------------------------------
// scan1: block-local exclusive scan of cnt -> pre, block sums, dinv.
__global__ void scan1_kernel(const int* __restrict__ cnt, int* __restrict__ pre,
                             int* __restrict__ bsum, float* __restrict__ dinv) {
    __shared__ int s[SCAN_B];
    int t = threadIdx.x;
    int g = blockIdx.x * SCAN_B + t;
    int v = (g < N_NODES) ? cnt[g] : 0;
    if (g < N_NODES) dinv[g] = rsqrtf((float)(v + 1));   // +1 self loop
    s[t] = v;
    __syncthreads();
    for (int o = 1; o < SCAN_B; o <<= 1) {
        int add = (t >= o) ? s[t - o] : 0;
        __syncthreads();
        s[t] += add;
        __syncthreads();
    }
    if (g < N_NODES) pre[g] = s[t] - v;
    if (t == SCAN_B - 1) bsum[blockIdx.x] = s[t];
}

// scan23: each block redundantly scans the 196 bsums in LDS, applies offset.
__global__ void scan23_kernel(int* __restrict__ rowptr, const int* __restrict__ bsum,
                              int* __restrict__ cursor) {
    __shared__ int s[256];
    int t = threadIdx.x;
    int v = (t < NB_SCAN) ? bsum[t] : 0;
    s[t] = v;
    __syncthreads();
    for (int o = 1; o < 256; o <<= 1) {
        int add = (t >= o) ? s[t - o] : 0;
        __syncthreads();
        s[t] += add;
        __syncthreads();
    }
    int excl = s[blockIdx.x] - bsum[blockIdx.x];
    int g = blockIdx.x * SCAN_B + t;
    if (g < N_NODES) {
        int r = rowptr[g] + excl;
        rowptr[g] = r;
        cursor[g] = r;
    }
    if (g == 0) rowptr[N_NODES] = N_EDGES;
}

// ---------------------------------------------------------------------------
// XCD-partitioned scatter from compacted int2 edges (half the bytes of the
// old int64 path). xcd = b%8 processes slice b/8, keeping only edges whose
// dst is in its node range -> ep writes and cursor atomics stay in one
// XCD's L2.
__global__ __launch_bounds__(256) void scatter_kernel(
        const int2* __restrict__ ep0, const float* __restrict__ dinv,
        int* __restrict__ cursor, int2* __restrict__ ep) {
    int xcd = blockIdx.x % N_XCD;
    int sl  = blockIdx.x / N_XCD;
    int lo  = xcd * NPX, hi = lo + NPX;
    int base = sl * SLICE;
#pragma unroll
    for (int j = 0; j < SLICE / 256; j++) {
        int e = base + j * 256 + threadIdx.x;
        if (e >= N_EDGES) continue;
        int2 sd = ep0[e];
        if (sd.y >= lo && sd.y < hi) {
            float w = dinv[sd.x];
            int p = atomicAdd(&cursor[sd.y], 1);
            ep[p] = make_int2(sd.x, __float_as_int(w));
        }
    }
}

// ---------------------------------------------------------------------------
// 64-wide aggregation, 2 edges per wave-load: lane = (half<<5)|col,
// half-wave 0 takes even-j edges, half-wave 1 odd-j; each lane loads a uint
// (2 bf16 features 2*col, 2*col+1) -> 256B per load instruction.
__device__ __forceinline__ float2 agg_node64(int e0, int e1, int2 pr0,
                                             const int2* __restrict__ ep,
                                             const unsigned int* __restrict__ gw,
                                             int lane, float2 acc) {
    int half = lane >> 5;
    int col  = lane & 31;
    int2 pr = pr0;
    for (int base = e0; base < e1; base += 64) {
        int cnt = e1 - base; cnt = cnt > 64 ? 64 : cnt;      // uniform
        int j = 0;
        for (; j + 16 <= cnt; j += 16) {                     // 8 pairs, unmasked
            unsigned int fv[8]; float wv[8];
#pragma unroll
            for (int u = 0; u < 8; u++) {
                int j0 = j + 2 * u;
                int sa = __builtin_amdgcn_readlane(pr.x, j0);
                int sb = __builtin_amdgcn_readlane(pr.x, j0 + 1);
                int wa = __builtin_amdgcn_readlane(pr.y, j0);
                int wb = __builtin_amdgcn_readlane(pr.y, j0 + 1);
                int s  = half ? sb : sa;
                wv[u]  = __int_as_float(half ? wb : wa);
                fv[u]  = gw[(size_t)s * 32 + col];
            }
#pragma unroll
            for (int u = 0; u < 8; u++) {
                acc.x = fmaf(wv[u], __uint_as_float(fv[u] << 16),          acc.x);
                acc.y = fmaf(wv[u], __uint_as_float(fv[u] & 0xffff0000u),  acc.y);
            }
        }
        for (; j < cnt; j += 8) {                            // 4 pairs, masked
            unsigned int fv[4]; float wv[4];
#pragma unroll
            for (int u = 0; u < 4; u++) {
                int j0 = j + 2 * u, j1 = j0 + 1;
                int ia = j0 < 63 ? j0 : 63;
                int ib = j1 < 63 ? j1 : 63;
                int sa = __builtin_amdgcn_readlane(pr.x, ia);
                int sb = __builtin_amdgcn_readlane(pr.x, ib);
                float wa = (j0 < cnt) ? __int_as_float(__builtin_amdgcn_readlane(pr.y, ia)) : 0.0f;
                float wb = (j1 < cnt) ? __int_as_float(__builtin_amdgcn_readlane(pr.y, ib)) : 0.0f;
                int s  = half ? sb : sa;
                wv[u]  = half ? wb : wa;
                fv[u]  = gw[(size_t)s * 32 + col];
            }
#pragma unroll
            for (int u = 0; u < 4; u++) {
                acc.x = fmaf(wv[u], __uint_as_float(fv[u] << 16),          acc.x);
                acc.y = fmaf(wv[u], __uint_as_float(fv[u] & 0xffff0000u),  acc.y);
            }
        }
        int nb = base + 64;
        if (nb < e1) {                                       // rare extra batch
            int idx = nb + lane;
            pr = ep[idx < N_EDGES ? idx : (N_EDGES - 1)];
        }
    }
    return acc;
}

// 32-wide aggregation, 4 edges per wave-load: lane = (qc<<4)|col,
// quarter-wave qc takes edges j%4==qc; lane loads uint (features 2*col,+1).
__device__ __forceinline__ float2 agg_node32(int e0, int e1, int2 pr0,
                                             const int2* __restrict__ ep,
                                             const unsigned int* __restrict__ xw,
                                             int lane, float2 acc) {
    int qc  = lane >> 4;
    int col = lane & 15;
    int2 pr = pr0;
    for (int base = e0; base < e1; base += 64) {
        int cnt = e1 - base; cnt = cnt > 64 ? 64 : cnt;
        int j = 0;
        for (; j + 16 <= cnt; j += 16) {                     // 4 quads, unmasked
            unsigned int fv[4]; float wv[4];
#pragma unroll
            for (int u = 0; u < 4; u++) {
                int j0 = j + 4 * u;
                int s0 = __builtin_amdgcn_readlane(pr.x, j0);
                int s1 = __builtin_amdgcn_readlane(pr.x, j0 + 1);
                int s2 = __builtin_amdgcn_readlane(pr.x, j0 + 2);
                int s3 = __builtin_amdgcn_readlane(pr.x, j0 + 3);
                int w0 = __builtin_amdgcn_readlane(pr.y, j0);
                int w1 = __builtin_amdgcn_readlane(pr.y, j0 + 1);
                int w2 = __builtin_amdgcn_readlane(pr.y, j0 + 2);
                int w3 = __builtin_amdgcn_readlane(pr.y, j0 + 3);
                int s  = qc == 0 ? s0 : qc == 1 ? s1 : qc == 2 ? s2 : s3;
                int w  = qc == 0 ? w0 : qc == 1 ? w1 : qc == 2 ? w2 : w3;
                wv[u]  = __int_as_float(w);
                fv[u]  = xw[(size_t)s * 16 + col];
            }
#pragma unroll
            for (int u = 0; u < 4; u++) {
                acc.x = fmaf(wv[u], __uint_as_float(fv[u] << 16),          acc.x);
                acc.y = fmaf(wv[u], __uint_as_float(fv[u] & 0xffff0000u),  acc.y);
            }
        }
        for (; j < cnt; j += 8) {                            // 2 quads, masked
            unsigned int fv[2]; float wv[2];
#pragma unroll
            for (int u = 0; u < 2; u++) {
                int j0 = j + 4 * u;
                int i0 = j0     < 63 ? j0     : 63;
                int i1 = j0 + 1 < 63 ? j0 + 1 : 63;
                int i2 = j0 + 2 < 63 ? j0 + 2 : 63;
                int i3 = j0 + 3 < 63 ? j0 + 3 : 63;
                int s0 = __builtin_amdgcn_readlane(pr.x, i0);
                int s1 = __builtin_amdgcn_readlane(pr.x, i1);
                int s2 = __builtin_amdgcn_readlane(pr.x, i2);
                int s3 = __builtin_amdgcn_readlane(pr.x, i3);
                float w0 = (j0     < cnt) ? __int_as_float(__builtin_amdgcn_readlane(pr.y, i0)) : 0.0f;
                float w1 = (j0 + 1 < cnt) ? __int_as_float(__builtin_amdgcn_readlane(pr.y, i1)) : 0.0f;
                float w2 = (j0 + 2 < cnt) ? __int_as_float(__builtin_amdgcn_readlane(pr.y, i2)) : 0.0f;
                float w3 = (j0 + 3 < cnt) ? __int_as_float(__builtin_amdgcn_readlane(pr.y, i3)) : 0.0f;
                int s  = qc == 0 ? s0 : qc == 1 ? s1 : qc == 2 ? s2 : s3;
                wv[u]  = qc == 0 ? w0 : qc == 1 ? w1 : qc == 2 ? w2 : w3;
                fv[u]  = xw[(size_t)s * 16 + col];
            }
#pragma unroll
            for (int u = 0; u < 2; u++) {
                acc.x = fmaf(wv[u], __uint_as_float(fv[u] << 16),          acc.x);
                acc.y = fmaf(wv[u], __uint_as_float(fv[u] & 0xffff0000u),  acc.y);
            }
        }
        int nb = base + 64;
        if (nb < e1) {
            int idx = nb + lane;
            pr = ep[idx < N_EDGES ? idx : (N_EDGES - 1)];
        }
    }
    return acc;
}

// ---------------------------------------------------------------------------
// Fused layer 1: q = normAgg(xb) [32-wide, f32], out = relu(q @ W1 + b1).
// A(XW) == (AX)W, so aggregate the 32-wide input (half the gather bytes of
// the old 64-wide pre-GEMM layout), then apply W1 per node via wave-local
// LDS broadcast (no barrier: same wave writes+reads its own 64-float slot).
__global__ __launch_bounds__(256, 4) void fused_layer32_kernel(
        const int* __restrict__ rowptr, const int2* __restrict__ ep,
        const float* __restrict__ dinv, const unsigned short* __restrict__ xb,
        const float* __restrict__ W1, const float* __restrict__ b1,
        unsigned short* __restrict__ out) {
    __shared__ float sq[4 * 64];
    int lane = threadIdx.x & 63;
    int wav  = threadIdx.x >> 6;
    int qc   = lane >> 4;
    const unsigned int* xw = (const unsigned int*)xb;
    float wcol[IN_DIM];
#pragma unroll
    for (int k = 0; k < IN_DIM; k++) wcol[k] = W1[k * 64 + lane];
    float bb = b1[lane];
    int wid = __builtin_amdgcn_readfirstlane((int)((blockIdx.x * blockDim.x + threadIdx.x) >> 6));
    int nw  = (gridDim.x * blockDim.x) >> 6;
    int v = wid;
    if (v >= N_NODES) return;
    int e0 = rowptr[v], e1 = rowptr[v + 1];
    float dv = dinv[v];
    unsigned int hv = xw[(size_t)v * 16 + (lane & 15)];
    int i0 = e0 + lane;
    int2 pr = ep[i0 < N_EDGES ? i0 : (N_EDGES - 1)];
    while (v < N_NODES) {
        int vn = v + nw;
        int e0n = 0, e1n = 0;
        float dvn = 0.0f;
        unsigned int hvn = 0;
        int2 prn = make_int2(0, 0);
        if (vn < N_NODES) {                                  // prefetch next node
            e0n = rowptr[vn]; e1n = rowptr[vn + 1];
            dvn = dinv[vn];
            hvn = xw[(size_t)vn * 16 + (lane & 15)];
            int in0 = e0n + lane;
            prn = ep[in0 < N_EDGES ? in0 : (N_EDGES - 1)];
        }
        float sv = (qc == 0) ? dv : 0.0f;                    // self term once
        float2 acc;
        acc.x = sv * __uint_as_float(hv << 16);
        acc.y = sv * __uint_as_float(hv & 0xffff0000u);
        acc = agg_node32(e0, e1, pr, ep, xw, lane, acc);
        acc.x += __shfl_xor(acc.x, 16);
        acc.y += __shfl_xor(acc.y, 16);
        acc.x += __shfl_xor(acc.x, 32);
        acc.y += __shfl_xor(acc.y, 32);
        float qx = dv * acc.x, qy = dv * acc.y;
        if (lane < 16) ((float2*)sq)[wav * 32 + lane] = make_float2(qx, qy);
        float o = bb;
        const float4* q4 = (const float4*)(sq + wav * 64);
#pragma unroll
        for (int c = 0; c < IN_DIM / 4; c++) {
            float4 t = q4[c];
            o = fmaf(t.x, wcol[4 * c + 0], o);
            o = fmaf(t.y, wcol[4 * c + 1], o);
            o = fmaf(t.z, wcol[4 * c + 2], o);
            o = fmaf(t.w, wcol[4 * c + 3], o);
        }
        out[(size_t)v * 64 + lane] = f2bf(fmaxf(o, 0.0f));
        v = vn; e0 = e0n; e1 = e1n; dv = dvn; hv = hvn; pr = prn;
    }
}

// Fused layer 2: q = normAgg(g) [64-wide, f32], out = relu(q @ W + b).
__global__ __launch_bounds__(256, 4) void fused_layer64_kernel(
        const int* __restrict__ rowptr, const int2* __restrict__ ep,
        const float* __restrict__ dinv, const unsigned short* __restrict__ g,
        const float* __restrict__ W, const float* __restrict__ bias,
        unsigned short* __restrict__ out) {
    __shared__ float sq[4 * 64];
    int lane = threadIdx.x & 63;
    int wav  = threadIdx.x >> 6;
    int half = lane >> 5;
    const unsigned int* gw = (const unsigned int*)g;
    float wcol[HIDDEN];
#pragma unroll
    for (int k = 0; k < HIDDEN; k++) wcol[k] = W[k * 64 + lane];
    float bb = bias[lane];
    int wid = __builtin_amdgcn_readfirstlane((int)((blockIdx.x * blockDim.x + threadIdx.x) >> 6));
    int nw  = (gridDim.x * blockDim.x) >> 6;
    int v = wid;
    if (v >= N_NODES) return;
    int e0 = rowptr[v], e1 = rowptr[v + 1];
    float dv = dinv[v];
    unsigned int hv = gw[(size_t)v * 32 + (lane & 31)];
    int i0 = e0 + lane;
    int2 pr = ep[i0 < N_EDGES ? i0 : (N_EDGES - 1)];
    while (v < N_NODES) {
        int vn = v + nw;
        int e0n = 0, e1n = 0;
        float dvn = 0.0f;
        unsigned int hvn = 0;
        int2 prn = make_int2(0, 0);
        if (vn < N_NODES) {
            e0n = rowptr[vn]; e1n = rowptr[vn + 1];
            dvn = dinv[vn];
            hvn = gw[(size_t)vn * 32 + (lane & 31)];
            int in0 = e0n + lane;
            prn = ep[in0 < N_EDGES ? in0 : (N_EDGES - 1)];
        }
        float sv = half ? 0.0f : dv;
        float2 acc;
        acc.x = sv * __uint_as_float(hv << 16);
        acc.y = sv * __uint_as_float(hv & 0xffff0000u);
        acc = agg_node64(e0, e1, pr, ep, gw, lane, acc);
        acc.x += __shfl_xor(acc.x, 32);
        acc.y += __shfl_xor(acc.y, 32);
        float qx = dv * acc.x, qy = dv * acc.y;
        if (lane < 32) ((float2*)sq)[wav * 32 + lane] = make_float2(qx, qy);
        float o = bb;
        const float4* q4 = (const float4*)(sq + wav * 64);
#pragma unroll
        for (int c = 0; c < HIDDEN / 4; c++) {
            float4 t = q4[c];
            o = fmaf(t.x, wcol[4 * c + 0], o);
            o = fmaf(t.y, wcol[4 * c + 1], o);
            o = fmaf(t.z, wcol[4 * c + 2], o);
            o = fmaf(t.w, wcol[4 * c + 3], o);
        }
        out[(size_t)v * 64 + lane] = f2bf(fmaxf(o, 0.0f));
        v = vn; e0 = e0n; e1 = e1n; dv = dvn; hv = hvn; pr = prn;
    }
}

// Fused heads: q = normAgg(h2); mu = q@Wmu+bmu (lanes<32), lv = q@Wlv+blv
// (lanes>=32); z = mu + exp(.5 lv) * eps. d_out = [z | mu | lv] fp32.
__global__ __launch_bounds__(256, 4) void fused_head_kernel(
        const int* __restrict__ rowptr, const int2* __restrict__ ep,
        const float* __restrict__ dinv, const unsigned short* __restrict__ g,
        const float* __restrict__ Wmu, const float* __restrict__ Wlv,
        const float* __restrict__ bmu, const float* __restrict__ blv,
        const float* __restrict__ eps, float* __restrict__ outz) {
    __shared__ float sq[4 * 64];
    int lane = threadIdx.x & 63;
    int wav  = threadIdx.x >> 6;
    int half = lane >> 5;
    int f = lane & 31;
    bool hi = lane >= 32;
    const unsigned int* gw = (const unsigned int*)g;
    float wcol[HIDDEN];
#pragma unroll
    for (int k = 0; k < HIDDEN; k++)
        wcol[k] = hi ? Wlv[k * 32 + f] : Wmu[k * 32 + f];
    float bb = hi ? blv[f] : bmu[f];
    float* z  = outz;
    float* mu = outz + (size_t)N_NODES * Z_DIM;
    float* lv = outz + 2 * (size_t)N_NODES * Z_DIM;
    int wid = __builtin_amdgcn_readfirstlane((int)((blockIdx.x * blockDim.x + threadIdx.x) >> 6));
    int nw  = (gridDim.x * blockDim.x) >> 6;
    int v = wid;
    if (v >= N_NODES) return;
    int e0 = rowptr[v], e1 = rowptr[v + 1];
    float dv = dinv[v];
    unsigned int hv = gw[(size_t)v * 32 + (lane & 31)];
    int i0 = e0 + lane;
    int2 pr = ep[i0 < N_EDGES ? i0 : (N_EDGES - 1)];
    while (v < N_NODES) {
        int vn = v + nw;
        int e0n = 0, e1n = 0;
        float dvn = 0.0f;
        unsigned int hvn = 0;
        int2 prn = make_int2(0, 0);
        if (vn < N_NODES) {
            e0n = rowptr[vn]; e1n = rowptr[vn + 1];
            dvn = dinv[vn];
            hvn = gw[(size_t)vn * 32 + (lane & 31)];
            int in0 = e0n + lane;
            prn = ep[in0 < N_EDGES ? in0 : (N_EDGES - 1)];
        }
        float sv = half ? 0.0f : dv;
        float2 acc;
        acc.x = sv * __uint_as_float(hv << 16);
        acc.y = sv * __uint_as_float(hv & 0xffff0000u);
        acc = agg_node64(e0, e1, pr, ep, gw, lane, acc);
        acc.x += __shfl_xor(acc.x, 32);
        acc.y += __shfl_xor(acc.y, 32);
        float qx = dv * acc.x, qy = dv * acc.y;
        if (lane < 32) ((float2*)sq)[wav * 32 + lane] = make_float2(qx, qy);
        float m = bb;
        const float4* q4 = (const float4*)(sq + wav * 64);
#pragma unroll
        for (int c = 0; c < HIDDEN / 4; c++) {
            float4 t = q4[c];
            m = fmaf(t.x, wcol[4 * c + 0], m);
            m = fmaf(t.y, wcol[4 * c + 1], m);
            m = fmaf(t.z, wcol[4 * c + 2], m);
            m = fmaf(t.w, wcol[4 * c + 3], m);
        }
        float ev = eps[(size_t)v * Z_DIM + f];
        float t  = expf(0.5f * m) * ev;
        float tlo = __shfl(t, lane | 32);
        size_t o = (size_t)v * Z_DIM + f;
        if (!hi) { mu[o] = m; z[o] = m + tlo; }
        else     { lv[o] = m; }
        v = vn; e0 = e0n; e1 = e1n; dv = dvn; hv = hvn; pr = prn;
    }
}

// ---------------------------------------------------------------------------
extern "C" void kernel_launch(void* const* d_in, const int* in_sizes, int n_in,
                              void* d_out, int out_size, void* d_ws, size_t ws_size,
                              hipStream_t stream) {
    const float* x   = (const float*)d_in[0];
    const void*  ei  = d_in[1];
    const float* W1  = (const float*)d_in[2];
    const float* b1  = (const float*)d_in[3];
    const float* W2  = (const float*)d_in[4];
    const float* b2  = (const float*)d_in[5];
    const float* Wmu = (const float*)d_in[6];
    const float* bmu = (const float*)d_in[7];
    const float* Wlv = (const float*)d_in[8];
    const float* blv = (const float*)d_in[9];
    const float* eps = (const float*)d_in[10];
    float* out = (float*)d_out;
    (void)in_sizes; (void)n_in; (void)out_size; (void)ws_size;

    char* ws = (char*)d_ws;
    size_t off = 0;
    auto alloc = [&](size_t bytes) -> void* {
        void* p = ws + off;
        off += (bytes + 255) & ~(size_t)255;
        return p;
    };
    int2*           ep     = (int2*)alloc(sizeof(int2) * N_EDGES);   // 6.4 MB
    int2*           ep0    = (int2*)alloc(sizeof(int2) * N_EDGES);   // 6.4 MB
    int*            rowptr = (int*)alloc(sizeof(int) * (N_NODES + 1));
    int*            cursor = (int*)alloc(sizeof(int) * N_NODES);
    int*            cnt    = (int*)alloc(sizeof(int) * N_NODES);
    float*          dinv   = (float*)alloc(sizeof(float) * N_NODES);
    int*            flag   = (int*)alloc(sizeof(int) * 64);
    int*            bsum   = (int*)alloc(sizeof(int) * 256);
    unsigned short* xb     = (unsigned short*)alloc(sizeof(short) * (size_t)N_NODES * IN_DIM);  // 3.2 MB
    unsigned short* G      = (unsigned short*)alloc(sizeof(short) * (size_t)N_NODES * HIDDEN);  // 6.4 MB
    unsigned short* H      = (unsigned short*)alloc(sizeof(short) * (size_t)N_NODES * HIDDEN);  // 6.4 MB

    hipMemsetAsync(cnt, 0, sizeof(int) * N_NODES, stream);
    prep_kernel<<<(N_NODES * IN_DIM + 255) / 256, 256, 0, stream>>>(x, xb, ei, flag, cnt, ep0);
    scan1_kernel<<<NB_SCAN, SCAN_B, 0, stream>>>(cnt, rowptr, bsum, dinv);
    scan23_kernel<<<NB_SCAN, SCAN_B, 0, stream>>>(rowptr, bsum, cursor);
    scatter_kernel<<<SCAT_B, 256, 0, stream>>>(ep0, dinv, cursor, ep);
    // Layer 1: h1 = relu((A_norm x) W1 + b1)   [agg on 32-wide input]
    fused_layer32_kernel<<<FB, 256, 0, stream>>>(rowptr, ep, dinv, xb, W1, b1, H);
    // Layer 2: h2 = relu((A_norm h1) W2 + b2)
    fused_layer64_kernel<<<FB, 256, 0, stream>>>(rowptr, ep, dinv, H, W2, b2, G);
    // Heads: q = A_norm h2 ; mu = qWmu+bmu ; lv = qWlv+blv ; z = mu+exp(.5lv)eps
    fused_head_kernel<<<FB, 256, 0, stream>>>(rowptr, ep, dinv, G, Wmu, Wlv, bmu, blv, eps, out);
}

// Round 2
// 231.220 us; speedup vs baseline: 1.2863x; 1.1860x over previous
//
#include <hip/hip_runtime.h>
#include <math.h>

#define N_NODES 50000
#define N_EDGES 800000
#define IN_DIM 32
#define HIDDEN 64
#define Z_DIM 32
#define SCAN_B 256
#define NB_SCAN ((N_NODES + SCAN_B - 1) / SCAN_B)   // 196
#define N_XCD 8
#define NPX ((N_NODES + N_XCD - 1) / N_XCD)         // 6250 nodes per XCD range
#define SLICE 2048
#define N_SLICE ((N_EDGES + SLICE - 1) / SLICE)     // 391
#define SCAT_B (N_SLICE * N_XCD)                    // 3128 hist blocks
#define FB 2048                                     // 8192 waves for node kernels

// bf16 (stored as ushort) <-> f32 helpers, RNE
__device__ __forceinline__ float bf2f(unsigned short u) {
    return __uint_as_float(((unsigned int)u) << 16);
}
__device__ __forceinline__ unsigned short f2bf(float f) {
    unsigned int u = __float_as_uint(f);
    u += 0x7fffu + ((u >> 16) & 1u);
    return (unsigned short)(u >> 16);
}

// wave-local edge dtype detect: int64 LE values < 2^31 have all-zero odd words.
__device__ __forceinline__ int detect64(const int* raw) {
    int lane = threadIdx.x & 63;
    int odd = raw[2 * lane + 1];
    unsigned long long b = __ballot(odd != 0);
    return (b == 0ULL) ? 1 : 0;
}

// ---------------------------------------------------------------------------
// prep: x->bf16 convert + XCD-partitioned degree histogram + int32 edge
// compaction (ep0) + per-edge rank capture + publish flag.
// The hist atomicAdd's RETURN VALUE is the edge's within-node arrival rank;
// storing it makes the later scatter deterministic (no atomics, no re-read).
__global__ void prep_kernel(const float* __restrict__ x, unsigned short* __restrict__ xb,
                            const void* __restrict__ raw, int* __restrict__ flag,
                            int* __restrict__ cnt, int2* __restrict__ ep0,
                            int* __restrict__ rank) {
    int is64 = detect64((const int*)raw);
    int i = blockIdx.x * 256 + threadIdx.x;
    if (blockIdx.x == 0 && threadIdx.x == 0) *flag = is64;
    if (i < N_NODES * IN_DIM) xb[i] = f2bf(x[i]);
    if (blockIdx.x < SCAT_B) {
        int xcd = blockIdx.x % N_XCD;
        int sl  = blockIdx.x / N_XCD;
        int own = ((sl % N_XCD) == xcd) ? 1 : 0;    // designated compactor
        int lo  = xcd * NPX, hi = lo + NPX;
        int base = sl * SLICE;
#pragma unroll
        for (int j = 0; j < SLICE / 256; j++) {
            int e = base + j * 256 + threadIdx.x;
            if (e < N_EDGES) {
                int d = is64 ? (int)((const long long*)raw)[N_EDGES + e]
                             : ((const int*)raw)[N_EDGES + e];
                if (own) {
                    int s = is64 ? (int)((const long long*)raw)[e]
                                 : ((const int*)raw)[e];
                    ep0[e] = make_int2(s, d);
                }
                if (d >= lo && d < hi) rank[e] = atomicAdd(&cnt[d], 1);
            }
        }
    }
}

// ---------------------------------------------------------------------------
// scan1: block-local exclusive scan of cnt -> pre, block sums, dinv.
__global__ void scan1_kernel(const int* __restrict__ cnt, int* __restrict__ pre,
                             int* __restrict__ bsum, float* __restrict__ dinv) {
    __shared__ int s[SCAN_B];
    int t = threadIdx.x;
    int g = blockIdx.x * SCAN_B + t;
    int v = (g < N_NODES) ? cnt[g] : 0;
    if (g < N_NODES) dinv[g] = rsqrtf((float)(v + 1));   // +1 self loop
    s[t] = v;
    __syncthreads();
    for (int o = 1; o < SCAN_B; o <<= 1) {
        int add = (t >= o) ? s[t - o] : 0;
        __syncthreads();
        s[t] += add;
        __syncthreads();
    }
    if (g < N_NODES) pre[g] = s[t] - v;
    if (t == SCAN_B - 1) bsum[blockIdx.x] = s[t];
}

// scan23: each block redundantly scans the 196 bsums in LDS, applies offset.
__global__ void scan23_kernel(int* __restrict__ rowptr, const int* __restrict__ bsum) {
    __shared__ int s[256];
    int t = threadIdx.x;
    int v = (t < NB_SCAN) ? bsum[t] : 0;
    s[t] = v;
    __syncthreads();
    for (int o = 1; o < 256; o <<= 1) {
        int add = (t >= o) ? s[t - o] : 0;
        __syncthreads();
        s[t] += add;
        __syncthreads();
    }
    int excl = s[blockIdx.x] - bsum[blockIdx.x];
    int g = blockIdx.x * SCAN_B + t;
    if (g < N_NODES) rowptr[g] += excl;
    if (g == 0) rowptr[N_NODES] = N_EDGES;
}

// ---------------------------------------------------------------------------
// Deterministic scatter: single pass, no atomics. Slot = rowptr[dst] + rank.
__global__ __launch_bounds__(256) void scatter_kernel(
        const int2* __restrict__ ep0, const int* __restrict__ rank,
        const int* __restrict__ rowptr, const float* __restrict__ dinv,
        int2* __restrict__ ep) {
    int base = blockIdx.x * SLICE;
#pragma unroll
    for (int j = 0; j < SLICE / 256; j++) {
        int e = base + j * 256 + threadIdx.x;
        if (e < N_EDGES) {
            int2 sd = ep0[e];
            int p = rowptr[sd.y] + rank[e];
            ep[p] = make_int2(sd.x, __float_as_int(dinv[sd.x]));
        }
    }
}

// ---------------------------------------------------------------------------
// 64-wide aggregation, uint2 loads: lane = (gsel<<4)|c; 16 lanes x 8B cover a
// 128B row -> 4 edges per wave-load (512B/inst). Per-lane edge index comes
// from ds_bpermute (no readlane ladder, no chunk/tail split). OOB lanes clamp
// to edge cnt-1 (re-reads an already-fetched line) with weight 0.
__device__ __forceinline__ void agg_body64(int e0, int e1, int2 pr,
                                           const int2* __restrict__ ep,
                                           const uint2* __restrict__ g2,
                                           int lane, float acc[4]) {
    int gsel = lane >> 4;
    int c    = lane & 15;
    for (int base = e0; base < e1; base += 64) {
        int cnt = e1 - base; cnt = cnt > 64 ? 64 : cnt;      // uniform
        for (int j = 0; j < cnt; j += 16) {
            uint2 fv[4]; float wv[4];
#pragma unroll
            for (int u = 0; u < 4; u++) {
                int idx = j + u * 4 + gsel;
                int cl  = idx < cnt ? idx : cnt - 1;
                int s   = __builtin_amdgcn_ds_bpermute(cl << 2, pr.x);
                int w   = __builtin_amdgcn_ds_bpermute(cl << 2, pr.y);
                wv[u]   = idx < cnt ? __int_as_float(w) : 0.0f;
                fv[u]   = g2[(size_t)s * 16 + c];
            }
#pragma unroll
            for (int u = 0; u < 4; u++) {
                acc[0] = fmaf(wv[u], __uint_as_float(fv[u].x << 16),         acc[0]);
                acc[1] = fmaf(wv[u], __uint_as_float(fv[u].x & 0xffff0000u), acc[1]);
                acc[2] = fmaf(wv[u], __uint_as_float(fv[u].y << 16),         acc[2]);
                acc[3] = fmaf(wv[u], __uint_as_float(fv[u].y & 0xffff0000u), acc[3]);
            }
        }
        int nb = base + 64;
        if (nb < e1) {                                       // rare extra batch
            int idx = nb + lane;
            pr = ep[idx < N_EDGES ? idx : (N_EDGES - 1)];
        }
    }
}

// 32-wide aggregation, uint2 loads: lane = (gsel<<3)|c; 8 lanes x 8B cover a
// 64B row -> 8 edges per wave-load (512B/inst).
__device__ __forceinline__ void agg_body32(int e0, int e1, int2 pr,
                                           const int2* __restrict__ ep,
                                           const uint2* __restrict__ x2,
                                           int lane, float acc[4]) {
    int gsel = lane >> 3;
    int c    = lane & 7;
    for (int base = e0; base < e1; base += 64) {
        int cnt = e1 - base; cnt = cnt > 64 ? 64 : cnt;
        for (int j = 0; j < cnt; j += 16) {
            uint2 fv[2]; float wv[2];
#pragma unroll
            for (int u = 0; u < 2; u++) {
                int idx = j + u * 8 + gsel;
                int cl  = idx < cnt ? idx : cnt - 1;
                int s   = __builtin_amdgcn_ds_bpermute(cl << 2, pr.x);
                int w   = __builtin_amdgcn_ds_bpermute(cl << 2, pr.y);
                wv[u]   = idx < cnt ? __int_as_float(w) : 0.0f;
                fv[u]   = x2[(size_t)s * 8 + c];
            }
#pragma unroll
            for (int u = 0; u < 2; u++) {
                acc[0] = fmaf(wv[u], __uint_as_float(fv[u].x << 16),         acc[0]);
                acc[1] = fmaf(wv[u], __uint_as_float(fv[u].x & 0xffff0000u), acc[1]);
                acc[2] = fmaf(wv[u], __uint_as_float(fv[u].y << 16),         acc[2]);
                acc[3] = fmaf(wv[u], __uint_as_float(fv[u].y & 0xffff0000u), acc[3]);
            }
        }
        int nb = base + 64;
        if (nb < e1) {
            int idx = nb + lane;
            pr = ep[idx < N_EDGES ? idx : (N_EDGES - 1)];
        }
    }
}

// ---------------------------------------------------------------------------
// Fused layer 1: q = normAgg(xb) [32-wide, f32], out = relu(q @ W1 + b1).
__global__ __launch_bounds__(256, 4) void fused_layer32_kernel(
        const int* __restrict__ rowptr, const int2* __restrict__ ep,
        const float* __restrict__ dinv, const unsigned short* __restrict__ xb,
        const float* __restrict__ W1, const float* __restrict__ b1,
        unsigned short* __restrict__ out) {
    __shared__ float sq[4 * 32];
    int lane = threadIdx.x & 63;
    int wav  = threadIdx.x >> 6;
    int gsel = lane >> 3;
    int c    = lane & 7;
    const uint2* x2 = (const uint2*)xb;
    float wcol[IN_DIM];
#pragma unroll
    for (int k = 0; k < IN_DIM; k++) wcol[k] = W1[k * 64 + lane];
    float bb = b1[lane];
    int wid = __builtin_amdgcn_readfirstlane((int)((blockIdx.x * blockDim.x + threadIdx.x) >> 6));
    int nw  = (gridDim.x * blockDim.x) >> 6;
    int v = wid;
    if (v >= N_NODES) return;
    int e0 = rowptr[v], e1 = rowptr[v + 1];
    float dv = dinv[v];
    uint2 hv = x2[(size_t)v * 8 + c];
    int i0 = e0 + lane;
    int2 pr = ep[i0 < N_EDGES ? i0 : (N_EDGES - 1)];
    while (v < N_NODES) {
        int vn = v + nw;
        int e0n = 0, e1n = 0;
        float dvn = 0.0f;
        uint2 hvn = make_uint2(0, 0);
        int2 prn = make_int2(0, 0);
        if (vn < N_NODES) {                                  // prefetch next node
            e0n = rowptr[vn]; e1n = rowptr[vn + 1];
            dvn = dinv[vn];
            hvn = x2[(size_t)vn * 8 + c];
            int in0 = e0n + lane;
            prn = ep[in0 < N_EDGES ? in0 : (N_EDGES - 1)];
        }
        float sv = (gsel == 0) ? dv : 0.0f;                  // self term once
        float acc[4];
        acc[0] = sv * __uint_as_float(hv.x << 16);
        acc[1] = sv * __uint_as_float(hv.x & 0xffff0000u);
        acc[2] = sv * __uint_as_float(hv.y << 16);
        acc[3] = sv * __uint_as_float(hv.y & 0xffff0000u);
        agg_body32(e0, e1, pr, ep, x2, lane, acc);
#pragma unroll
        for (int i = 0; i < 4; i++) {
            acc[i] += __shfl_xor(acc[i], 8);
            acc[i] += __shfl_xor(acc[i], 16);
            acc[i] += __shfl_xor(acc[i], 32);
        }
        if (lane < 8)
            ((float4*)(sq + wav * 32))[c] =
                make_float4(dv * acc[0], dv * acc[1], dv * acc[2], dv * acc[3]);
        float o = bb;
        const float4* q4 = (const float4*)(sq + wav * 32);
#pragma unroll
        for (int k = 0; k < IN_DIM / 4; k++) {
            float4 t = q4[k];
            o = fmaf(t.x, wcol[4 * k + 0], o);
            o = fmaf(t.y, wcol[4 * k + 1], o);
            o = fmaf(t.z, wcol[4 * k + 2], o);
            o = fmaf(t.w, wcol[4 * k + 3], o);
        }
        out[(size_t)v * 64 + lane] = f2bf(fmaxf(o, 0.0f));
        v = vn; e0 = e0n; e1 = e1n; dv = dvn; hv = hvn; pr = prn;
    }
}

// Fused layer 2: q = normAgg(g) [64-wide, f32], out = relu(q @ W + b).
__global__ __launch_bounds__(256, 4) void fused_layer64_kernel(
        const int* __restrict__ rowptr, const int2* __restrict__ ep,
        const float* __restrict__ dinv, const unsigned short* __restrict__ g,
        const float* __restrict__ W, const float* __restrict__ bias,
        unsigned short* __restrict__ out) {
    __shared__ float sq[4 * 64];
    int lane = threadIdx.x & 63;
    int wav  = threadIdx.x >> 6;
    int gsel = lane >> 4;
    int c    = lane & 15;
    const uint2* g2 = (const uint2*)g;
    float wcol[HIDDEN];
#pragma unroll
    for (int k = 0; k < HIDDEN; k++) wcol[k] = W[k * 64 + lane];
    float bb = bias[lane];
    int wid = __builtin_amdgcn_readfirstlane((int)((blockIdx.x * blockDim.x + threadIdx.x) >> 6));
    int nw  = (gridDim.x * blockDim.x) >> 6;
    int v = wid;
    if (v >= N_NODES) return;
    int e0 = rowptr[v], e1 = rowptr[v + 1];
    float dv = dinv[v];
    uint2 hv = g2[(size_t)v * 16 + c];
    int i0 = e0 + lane;
    int2 pr = ep[i0 < N_EDGES ? i0 : (N_EDGES - 1)];
    while (v < N_NODES) {
        int vn = v + nw;
        int e0n = 0, e1n = 0;
        float dvn = 0.0f;
        uint2 hvn = make_uint2(0, 0);
        int2 prn = make_int2(0, 0);
        if (vn < N_NODES) {
            e0n = rowptr[vn]; e1n = rowptr[vn + 1];
            dvn = dinv[vn];
            hvn = g2[(size_t)vn * 16 + c];
            int in0 = e0n + lane;
            prn = ep[in0 < N_EDGES ? in0 : (N_EDGES - 1)];
        }
        float sv = (gsel == 0) ? dv : 0.0f;
        float acc[4];
        acc[0] = sv * __uint_as_float(hv.x << 16);
        acc[1] = sv * __uint_as_float(hv.x & 0xffff0000u);
        acc[2] = sv * __uint_as_float(hv.y << 16);
        acc[3] = sv * __uint_as_float(hv.y & 0xffff0000u);
        agg_body64(e0, e1, pr, ep, g2, lane, acc);
#pragma unroll
        for (int i = 0; i < 4; i++) {
            acc[i] += __shfl_xor(acc[i], 16);
            acc[i] += __shfl_xor(acc[i], 32);
        }
        if (lane < 16)
            ((float4*)(sq + wav * 64))[c] =
                make_float4(dv * acc[0], dv * acc[1], dv * acc[2], dv * acc[3]);
        float o = bb;
        const float4* q4 = (const float4*)(sq + wav * 64);
#pragma unroll
        for (int k = 0; k < HIDDEN / 4; k++) {
            float4 t = q4[k];
            o = fmaf(t.x, wcol[4 * k + 0], o);
            o = fmaf(t.y, wcol[4 * k + 1], o);
            o = fmaf(t.z, wcol[4 * k + 2], o);
            o = fmaf(t.w, wcol[4 * k + 3], o);
        }
        out[(size_t)v * 64 + lane] = f2bf(fmaxf(o, 0.0f));
        v = vn; e0 = e0n; e1 = e1n; dv = dvn; hv = hvn; pr = prn;
    }
}

// Fused heads: q = normAgg(h2); mu = q@Wmu+bmu (lanes<32), lv = q@Wlv+blv
// (lanes>=32); z = mu + exp(.5 lv) * eps. d_out = [z | mu | lv] fp32.
__global__ __launch_bounds__(256, 4) void fused_head_kernel(
        const int* __restrict__ rowptr, const int2* __restrict__ ep,
        const float* __restrict__ dinv, const unsigned short* __restrict__ g,
        const float* __restrict__ Wmu, const float* __restrict__ Wlv,
        const float* __restrict__ bmu, const float* __restrict__ blv,
        const float* __restrict__ eps, float* __restrict__ outz) {
    __shared__ float sq[4 * 64];
    int lane = threadIdx.x & 63;
    int wav  = threadIdx.x >> 6;
    int gsel = lane >> 4;
    int c    = lane & 15;
    int f = lane & 31;
    bool hi = lane >= 32;
    const uint2* g2 = (const uint2*)g;
    float wcol[HIDDEN];
#pragma unroll
    for (int k = 0; k < HIDDEN; k++)
        wcol[k] = hi ? Wlv[k * 32 + f] : Wmu[k * 32 + f];
    float bb = hi ? blv[f] : bmu[f];
    float* z  = outz;
    float* mu = outz + (size_t)N_NODES * Z_DIM;
    float* lv = outz + 2 * (size_t)N_NODES * Z_DIM;
    int wid = __builtin_amdgcn_readfirstlane((int)((blockIdx.x * blockDim.x + threadIdx.x) >> 6));
    int nw  = (gridDim.x * blockDim.x) >> 6;
    int v = wid;
    if (v >= N_NODES) return;
    int e0 = rowptr[v], e1 = rowptr[v + 1];
    float dv = dinv[v];
    uint2 hv = g2[(size_t)v * 16 + c];
    int i0 = e0 + lane;
    int2 pr = ep[i0 < N_EDGES ? i0 : (N_EDGES - 1)];
    while (v < N_NODES) {
        int vn = v + nw;
        int e0n = 0, e1n = 0;
        float dvn = 0.0f;
        uint2 hvn = make_uint2(0, 0);
        int2 prn = make_int2(0, 0);
        if (vn < N_NODES) {
            e0n = rowptr[vn]; e1n = rowptr[vn + 1];
            dvn = dinv[vn];
            hvn = g2[(size_t)vn * 16 + c];
            int in0 = e0n + lane;
            prn = ep[in0 < N_EDGES ? in0 : (N_EDGES - 1)];
        }
        float sv = (gsel == 0) ? dv : 0.0f;
        float acc[4];
        acc[0] = sv * __uint_as_float(hv.x << 16);
        acc[1] = sv * __uint_as_float(hv.x & 0xffff0000u);
        acc[2] = sv * __uint_as_float(hv.y << 16);
        acc[3] = sv * __uint_as_float(hv.y & 0xffff0000u);
        agg_body64(e0, e1, pr, ep, g2, lane, acc);
#pragma unroll
        for (int i = 0; i < 4; i++) {
            acc[i] += __shfl_xor(acc[i], 16);
            acc[i] += __shfl_xor(acc[i], 32);
        }
        if (lane < 16)
            ((float4*)(sq + wav * 64))[c] =
                make_float4(dv * acc[0], dv * acc[1], dv * acc[2], dv * acc[3]);
        float m = bb;
        const float4* q4 = (const float4*)(sq + wav * 64);
#pragma unroll
        for (int k = 0; k < HIDDEN / 4; k++) {
            float4 t = q4[k];
            m = fmaf(t.x, wcol[4 * k + 0], m);
            m = fmaf(t.y, wcol[4 * k + 1], m);
            m = fmaf(t.z, wcol[4 * k + 2], m);
            m = fmaf(t.w, wcol[4 * k + 3], m);
        }
        float ev = eps[(size_t)v * Z_DIM + f];
        float t  = expf(0.5f * m) * ev;
        float tlo = __shfl(t, lane | 32);
        size_t o = (size_t)v * Z_DIM + f;
        if (!hi) { mu[o] = m; z[o] = m + tlo; }
        else     { lv[o] = m; }
        v = vn; e0 = e0n; e1 = e1n; dv = dvn; hv = hvn; pr = prn;
    }
}

// ---------------------------------------------------------------------------
extern "C" void kernel_launch(void* const* d_in, const int* in_sizes, int n_in,
                              void* d_out, int out_size, void* d_ws, size_t ws_size,
                              hipStream_t stream) {
    const float* x   = (const float*)d_in[0];
    const void*  ei  = d_in[1];
    const float* W1  = (const float*)d_in[2];
    const float* b1  = (const float*)d_in[3];
    const float* W2  = (const float*)d_in[4];
    const float* b2  = (const float*)d_in[5];
    const float* Wmu = (const float*)d_in[6];
    const float* bmu = (const float*)d_in[7];
    const float* Wlv = (const float*)d_in[8];
    const float* blv = (const float*)d_in[9];
    const float* eps = (const float*)d_in[10];
    float* out = (float*)d_out;
    (void)in_sizes; (void)n_in; (void)out_size; (void)ws_size;

    char* ws = (char*)d_ws;
    size_t off = 0;
    auto alloc = [&](size_t bytes) -> void* {
        void* p = ws + off;
        off += (bytes + 255) & ~(size_t)255;
        return p;
    };
    int2*           ep     = (int2*)alloc(sizeof(int2) * N_EDGES);   // 6.4 MB
    int2*           ep0    = (int2*)alloc(sizeof(int2) * N_EDGES);   // 6.4 MB
    int*            rank   = (int*)alloc(sizeof(int) * N_EDGES);     // 3.2 MB
    int*            rowptr = (int*)alloc(sizeof(int) * (N_NODES + 1));
    int*            cnt    = (int*)alloc(sizeof(int) * N_NODES);
    float*          dinv   = (float*)alloc(sizeof(float) * N_NODES);
    int*            flag   = (int*)alloc(sizeof(int) * 64);
    int*            bsum   = (int*)alloc(sizeof(int) * 256);
    unsigned short* xb     = (unsigned short*)alloc(sizeof(short) * (size_t)N_NODES * IN_DIM);  // 3.2 MB
    unsigned short* G      = (unsigned short*)alloc(sizeof(short) * (size_t)N_NODES * HIDDEN);  // 6.4 MB
    unsigned short* H      = (unsigned short*)alloc(sizeof(short) * (size_t)N_NODES * HIDDEN);  // 6.4 MB

    hipMemsetAsync(cnt, 0, sizeof(int) * N_NODES, stream);
    prep_kernel<<<(N_NODES * IN_DIM + 255) / 256, 256, 0, stream>>>(x, xb, ei, flag, cnt, ep0, rank);
    scan1_kernel<<<NB_SCAN, SCAN_B, 0, stream>>>(cnt, rowptr, bsum, dinv);
    scan23_kernel<<<NB_SCAN, SCAN_B, 0, stream>>>(rowptr, bsum);
    scatter_kernel<<<N_SLICE, 256, 0, stream>>>(ep0, rank, rowptr, dinv, ep);
    // Layer 1: h1 = relu((A_norm x) W1 + b1)   [agg on 32-wide input]
    fused_layer32_kernel<<<FB, 256, 0, stream>>>(rowptr, ep, dinv, xb, W1, b1, H);
    // Layer 2: h2 = relu((A_norm h1) W2 + b2)
    fused_layer64_kernel<<<FB, 256, 0, stream>>>(rowptr, ep, dinv, H, W2, b2, G);
    // Heads: q = A_norm h2 ; mu = qWmu+bmu ; lv = qWlv+blv ; z = mu+exp(.5lv)eps
    fused_head_kernel<<<FB, 256, 0, stream>>>(rowptr, ep, dinv, G, Wmu, Wlv, bmu, blv, eps, out);
}